// Round 12
// baseline (459.931 us; speedup 1.0000x reference)
//
#include <hip/hip_runtime.h>
#include <math.h>

#define NN 100000
#define NE 1600000
#define DIM 128
#define SCHUNK 1024
#define NBK 391        // ceil(NN/256) buckets of 256 nodes
#define ECH 4096       // edges per k_bucket block

typedef unsigned short u16;
typedef unsigned int u32;
typedef unsigned long long u64;
typedef __attribute__((ext_vector_type(8))) short bf16x8;
typedef __attribute__((ext_vector_type(4))) float f32x4;

__device__ inline u16 f2bf(float f) {
  union { float f; u32 u; } v; v.f = f;
  u32 r = v.u + 0x7FFF + ((v.u >> 16) & 1);   // round-to-nearest-even
  return (u16)(r >> 16);
}
__device__ inline float bflo(u32 u) { union { u32 u; float f; } v; v.u = u << 16; return v.f; }
__device__ inline float bfhi(u32 u) { union { u32 u; float f; } v; v.u = u & 0xFFFF0000u; return v.f; }
__device__ inline float sigm(float x) { return 1.0f / (1.0f + expf(-x)); }
__device__ inline int ntl(const int* p) { return __builtin_nontemporal_load(p); }

// ---------------- degree ----------------
__global__ void k_deg(const int* __restrict__ dst, int* __restrict__ deg) {
  int i = blockIdx.x * blockDim.x + threadIdx.x;
  if (i < NE) atomicAdd(&deg[ntl(dst + i)], 1);
}

// ---------------- exclusive prefix scan of deg -> offs (+ dinv fused) --------
__global__ void k_scan1(const int* __restrict__ deg, int* __restrict__ bsum) {
  __shared__ int sd[256];
  int t = threadIdx.x;
  int base = blockIdx.x * SCHUNK + t * 4;
  int s = 0;
#pragma unroll
  for (int j = 0; j < 4; ++j) { int idx = base + j; if (idx < NN) s += deg[idx]; }
  sd[t] = s; __syncthreads();
  for (int off = 128; off > 0; off >>= 1) {
    if (t < off) sd[t] += sd[t + off];
    __syncthreads();
  }
  if (t == 0) bsum[blockIdx.x] = sd[0];
}

__global__ void k_scan2(int* __restrict__ bsum, int nb) {   // nb <= 128
  __shared__ int sd[128];
  int t = threadIdx.x;
  int v = (t < nb) ? bsum[t] : 0;
  sd[t] = v; __syncthreads();
  for (int off = 1; off < 128; off <<= 1) {
    int x = (t >= off) ? sd[t - off] : 0;
    __syncthreads();
    sd[t] += x;
    __syncthreads();
  }
  if (t < nb) bsum[t] = sd[t] - v;
}

__global__ void k_scan3(const int* __restrict__ deg, const int* __restrict__ bsum,
                        int* __restrict__ offs, float* __restrict__ dinv) {
  __shared__ int ts[256];
  int t = threadIdx.x;
  int base = blockIdx.x * SCHUNK + t * 4;
  int v[4]; int loc = 0;
#pragma unroll
  for (int j = 0; j < 4; ++j) { int idx = base + j; v[j] = (idx < NN) ? deg[idx] : 0; loc += v[j]; }
  ts[t] = loc; __syncthreads();
  for (int off = 1; off < 256; off <<= 1) {
    int x = (t >= off) ? ts[t - off] : 0;
    __syncthreads();
    ts[t] += x;
    __syncthreads();
  }
  int run = bsum[blockIdx.x] + ts[t] - loc;
#pragma unroll
  for (int j = 0; j < 4; ++j) {
    int idx = base + j;
    if (idx < NN) {
      offs[idx] = run;
      dinv[idx] = rsqrtf((float)v[j] + 1.0f);
    }
    run += v[j];
  }
}

// ---------------- bucket pass: bin edges by dst>>8 into staging ----------------
__launch_bounds__(256)
__global__ void k_bucket(const int* __restrict__ src, const int* __restrict__ dst,
                         const int* __restrict__ offs, int* __restrict__ bcur,
                         uint2* __restrict__ bstage) {
  __shared__ int cnt[512];
  __shared__ int bl[512];
  __shared__ int gb[512];
  __shared__ int tmp[256];
  __shared__ uint2 st[ECH];
  int t = threadIdx.x;
  int e0 = blockIdx.x * ECH;
  cnt[t] = 0; cnt[t + 256] = 0;
  __syncthreads();
  int b_[16], r_[16]; u32 s_[16], y_[16];
#pragma unroll
  for (int k = 0; k < 16; ++k) {
    int i = e0 + k * 256 + t;
    b_[k] = -1;
    if (i < NE) {
      int d = ntl(dst + i);
      int bb = d >> 8;
      b_[k] = bb;
      s_[k] = (u32)ntl(src + i);
      y_[k] = ((u32)(d & 255) << 21) | (u32)i;
      r_[k] = atomicAdd(&cnt[bb], 1);
    }
  }
  __syncthreads();
  int c0 = cnt[2 * t], c1 = cnt[2 * t + 1];
  tmp[t] = c0 + c1;
  __syncthreads();
  for (int off = 1; off < 256; off <<= 1) {
    int v = (t >= off) ? tmp[t - off] : 0;
    __syncthreads();
    tmp[t] += v;
    __syncthreads();
  }
  int excl = tmp[t] - (c0 + c1);
  bl[2 * t] = excl; bl[2 * t + 1] = excl + c0;
  __syncthreads();
#pragma unroll
  for (int k = 0; k < 16; ++k)
    if (b_[k] >= 0) st[bl[b_[k]] + r_[k]] = make_uint2(s_[k], y_[k]);
  for (int b = t; b < 512; b += 256) {
    int n = cnt[b];
    gb[b] = (n > 0) ? atomicAdd(&bcur[b], n) : 0;
  }
  __syncthreads();
  for (int b = t; b < 512; b += 256) {
    int n = cnt[b];
    if (n > 0) {
      uint2* dp = bstage + offs[b << 8] + gb[b];
      const uint2* sp = st + bl[b];
      for (int j = 0; j < n; ++j) dp[j] = sp[j];
    }
  }
}

// ---------------- final fill: one block per bucket ----------------
__launch_bounds__(256)
__global__ void k_fillb(const uint2* __restrict__ bstage, const int* __restrict__ offs,
                        int* __restrict__ csr_src, int* __restrict__ csr_dst,
                        int* __restrict__ csr_eid) {
  __shared__ int curl[256];
  int t = threadIdx.x;
  int b = blockIdx.x;
  int nb0 = b << 8;
  curl[t] = 0;
  __syncthreads();
  int sbase = offs[nb0];
  int send = (b == NBK - 1) ? NE : offs[nb0 + 256];
  for (int j = sbase + t; j < send; j += 256) {
    u64 ev = __builtin_nontemporal_load((const u64*)(bstage + j));
    u32 ex = (u32)ev, ey = (u32)(ev >> 32);
    int dl = ey >> 21;
    int eid = ey & 0x1FFFFF;
    int pos = offs[nb0 + dl] + atomicAdd(&curl[dl], 1);
    csr_src[pos] = (int)ex;
    csr_dst[pos] = nb0 + dl;
    csr_eid[pos] = eid;
  }
}

// ---------------- pack all 3 W into MFMA B-frag order ----------------
__global__ void k_pack3(const float* __restrict__ W1, const float* __restrict__ W2,
                        const float* __restrict__ W3, u16* __restrict__ Wp1,
                        u16* __restrict__ Wp2, u16* __restrict__ Wp3) {
  int gid = blockIdx.x * blockDim.x + threadIdx.x;   // 3*16384
  int which = gid >> 14;
  int tid = gid & 16383;
  const float* W = which == 0 ? W1 : (which == 1 ? W2 : W3);
  u16* Wp = which == 0 ? Wp1 : (which == 1 ? Wp2 : Wp3);
  int b = tid & 7, j = (tid >> 3) & 15, kb = (tid >> 7) & 3, ks = (tid >> 9) & 3, ct = tid >> 11;
  int k = ks * 32 + kb * 8 + b, col = ct * 16 + j;
  Wp[tid] = f2bf(W[k * 128 + col]);
}

// ---------------- GEMM layer1: A = fp32 X (nt loads, in-register cvt) ----------------
__launch_bounds__(256)
__global__ void k_gemm1(const float* __restrict__ X, const u16* __restrict__ Wp,
                        const float* __restrict__ dinv, u16* __restrict__ hp) {
  __shared__ u16 ctile[4][2176];   // per-wave epilogue staging, 136-u16 row stride
  int t = threadIdx.x;
  int w = t >> 6, l = t & 63;
  int row0 = blockIdx.x * 64;
  int rbase = row0 + w * 16;

  int arow = rbase + (l & 15);
  arow = arow < NN ? arow : NN - 1;
  const float* ab = X + (size_t)arow * DIM + (l >> 4) * 8;
  bf16x8 a[4];
#pragma unroll
  for (int ks = 0; ks < 4; ++ks) {
    f32x4 f0 = __builtin_nontemporal_load((const f32x4*)(ab + ks * 32));
    f32x4 f1 = __builtin_nontemporal_load((const f32x4*)(ab + ks * 32 + 4));
    bf16x8 aa;
    aa[0] = (short)f2bf(f0[0]); aa[1] = (short)f2bf(f0[1]);
    aa[2] = (short)f2bf(f0[2]); aa[3] = (short)f2bf(f0[3]);
    aa[4] = (short)f2bf(f1[0]); aa[5] = (short)f2bf(f1[1]);
    aa[6] = (short)f2bf(f1[2]); aa[7] = (short)f2bf(f1[3]);
    a[ks] = aa;
  }

  f32x4 acc[8];
#pragma unroll
  for (int ct = 0; ct < 8; ++ct) {
    acc[ct] = (f32x4){0.f, 0.f, 0.f, 0.f};
#pragma unroll
    for (int ks = 0; ks < 4; ++ks) {
      bf16x8 bfr = *(const bf16x8*)&Wp[ct * 2048 + ks * 512 + (l >> 4) * 128 + (l & 15) * 8];
      acc[ct] = __builtin_amdgcn_mfma_f32_16x16x32_bf16(a[ks], bfr, acc[ct], 0, 0, 0);
    }
  }

  float dv[4];
#pragma unroll
  for (int v = 0; v < 4; ++v) {
    int rr = rbase + (l >> 4) * 4 + v;
    dv[v] = dinv[rr < NN ? rr : NN - 1];
  }
  u16* ct_lds = ctile[w];
#pragma unroll
  for (int ct = 0; ct < 8; ++ct) {
#pragma unroll
    for (int v = 0; v < 4; ++v) {
      int row = (l >> 4) * 4 + v;
      ct_lds[row * 136 + ct * 16 + (l & 15)] = f2bf(dv[v] * acc[ct][v]);
    }
  }
  __syncthreads();
#pragma unroll
  for (int rr = 0; rr < 4; ++rr) {
    int row = rr * 4 + (l >> 4);
    int grow = rbase + row;
    if (grow < NN)
      *(uint4*)&hp[(size_t)grow * DIM + (l & 15) * 8] =
          *(const uint4*)&ct_lds[row * 136 + (l & 15) * 8];
  }
}

// ---------------- FUSED: agg(layer l) + GEMM(layer l+1), 32 rows/block ----------------
__launch_bounds__(256)
__global__ void k_fused(const u16* __restrict__ hp, const int* __restrict__ csr_src,
                        const int* __restrict__ offs, const int* __restrict__ deg,
                        const float* __restrict__ dinv, const float* __restrict__ bias,
                        const u16* __restrict__ Wp, u16* __restrict__ hpo) {
  __shared__ u16 atile[4352];      // gather: 32 rows x 256 B swizzled (4096 u16);
                                   // reused as ctile: 4 waves x 16 x 68 (4352 u16)
  int t = threadIdx.x;
  int row0 = blockIdx.x * 32;      // NN = 3125 * 32 exact

  // ---- gather (agg) phase: 8 groups x 32 lanes, 4 passes ----
  {
    int g = t >> 5, l = t & 31;
    const uint2* hp2 = (const uint2*)hp;
    float4 bb = ((const float4*)bias)[l];
    for (int pass = 0; pass < 4; ++pass) {
      int row = pass * 8 + g;
      int n = row0 + row;
      float dn = dinv[n];
      int s = offs[n], cnt = deg[n];
      float a0 = 0.f, a1 = 0.f, a2 = 0.f, a3 = 0.f;
      int i = 0;
      for (; i + 8 <= cnt; i += 8) {
        int u[8];
#pragma unroll
        for (int k = 0; k < 8; ++k) u[k] = ntl(csr_src + s + i + k);
        uint2 v[8];
#pragma unroll
        for (int k = 0; k < 8; ++k) v[k] = hp2[(size_t)u[k] * 32 + l];
#pragma unroll
        for (int k = 0; k < 8; ++k) {
          a0 += bflo(v[k].x); a1 += bfhi(v[k].x); a2 += bflo(v[k].y); a3 += bfhi(v[k].y);
        }
      }
      for (; i + 4 <= cnt; i += 4) {
        int u[4];
#pragma unroll
        for (int k = 0; k < 4; ++k) u[k] = ntl(csr_src + s + i + k);
        uint2 v[4];
#pragma unroll
        for (int k = 0; k < 4; ++k) v[k] = hp2[(size_t)u[k] * 32 + l];
#pragma unroll
        for (int k = 0; k < 4; ++k) {
          a0 += bflo(v[k].x); a1 += bfhi(v[k].x); a2 += bflo(v[k].y); a3 += bfhi(v[k].y);
        }
      }
      for (; i < cnt; ++i) {
        int u = ntl(csr_src + s + i);
        uint2 v = hp2[(size_t)u * 32 + l];
        a0 += bflo(v.x); a1 += bfhi(v.x); a2 += bflo(v.y); a3 += bfhi(v.y);
      }
      uint2 sv = hp2[(size_t)n * 32 + l];
      float r0 = fmaxf(dn * (a0 + bflo(sv.x)) + bb.x, 0.f);
      float r1 = fmaxf(dn * (a1 + bfhi(sv.x)) + bb.y, 0.f);
      float r2 = fmaxf(dn * (a2 + bflo(sv.y)) + bb.z, 0.f);
      float r3 = fmaxf(dn * (a3 + bfhi(sv.y)) + bb.w, 0.f);
      ushort4 o; o.x = f2bf(r0); o.y = f2bf(r1); o.z = f2bf(r2); o.w = f2bf(r3);
      int byte = row * 256 + ((l * 8) ^ ((row & 7) << 4));
      *(ushort4*)((char*)atile + byte) = o;
    }
  }
  __syncthreads();

  // ---- GEMM phase: 4 waves = (row half) x (col half); 16 rows x 64 cols each ----
  int w = t >> 6, l = t & 63;
  int rbase = row0 + (w & 1) * 16;
  int arow = (w & 1) * 16 + (l & 15);
  int chalf = w >> 1;
  bf16x8 a[4];
#pragma unroll
  for (int ks = 0; ks < 4; ++ks) {
    int cb = ((l >> 4) * 16 + ks * 64) ^ ((arow & 7) << 4);
    a[ks] = *(const bf16x8*)((const char*)atile + arow * 256 + cb);
  }
  f32x4 acc[4];
#pragma unroll
  for (int ct = 0; ct < 4; ++ct) {
    int ctg = chalf * 4 + ct;
    acc[ct] = (f32x4){0.f, 0.f, 0.f, 0.f};
#pragma unroll
    for (int ks = 0; ks < 4; ++ks) {
      bf16x8 bfr = *(const bf16x8*)&Wp[ctg * 2048 + ks * 512 + (l >> 4) * 128 + (l & 15) * 8];
      acc[ct] = __builtin_amdgcn_mfma_f32_16x16x32_bf16(a[ks], bfr, acc[ct], 0, 0, 0);
    }
  }
  __syncthreads();   // all atile reads done before ctile reuse

  float dv[4];
#pragma unroll
  for (int v = 0; v < 4; ++v) dv[v] = dinv[rbase + (l >> 4) * 4 + v];
  u16* ct_lds = atile + w * 1088;    // 16 rows x 68 u16 per wave
#pragma unroll
  for (int ct = 0; ct < 4; ++ct) {
#pragma unroll
    for (int v = 0; v < 4; ++v) {
      int row = (l >> 4) * 4 + v;
      ct_lds[row * 68 + ct * 16 + (l & 15)] = f2bf(dv[v] * acc[ct][v]);
    }
  }
  __syncthreads();
#pragma unroll
  for (int rr = 0; rr < 2; ++rr) {
    int row = rr * 8 + (l >> 3);
    int grow = rbase + row;
    *(uint4*)&hpo[(size_t)grow * DIM + chalf * 64 + (l & 7) * 8] =
        *(const uint4*)&ct_lds[row * 68 + (l & 7) * 8];
  }
}

// ---------------- layer-3 aggregation: z = bf16( dn*(sum hp[u] + hp[n]) + b ) ----
__launch_bounds__(256)
__global__ void k_agg(const u16* __restrict__ hp, const int* __restrict__ csr_src,
                      const int* __restrict__ offs, const int* __restrict__ deg,
                      const float* __restrict__ dinv, const float* __restrict__ bias,
                      u16* __restrict__ outb) {
  int t = threadIdx.x;
  int g = t >> 5, l = t & 31;
  int n = blockIdx.x * 8 + g;          // NN/8 exact
  float dn = dinv[n];
  int s = offs[n], cnt = deg[n];
  const uint2* hp2 = (const uint2*)hp;
  float a0 = 0.f, a1 = 0.f, a2 = 0.f, a3 = 0.f;
  int i = 0;
  for (; i + 8 <= cnt; i += 8) {
    int u[8];
#pragma unroll
    for (int k = 0; k < 8; ++k) u[k] = ntl(csr_src + s + i + k);
    uint2 v[8];
#pragma unroll
    for (int k = 0; k < 8; ++k) v[k] = hp2[(size_t)u[k] * 32 + l];
#pragma unroll
    for (int k = 0; k < 8; ++k) {
      a0 += bflo(v[k].x); a1 += bfhi(v[k].x); a2 += bflo(v[k].y); a3 += bfhi(v[k].y);
    }
  }
  for (; i + 4 <= cnt; i += 4) {
    int u[4];
#pragma unroll
    for (int k = 0; k < 4; ++k) u[k] = ntl(csr_src + s + i + k);
    uint2 v[4];
#pragma unroll
    for (int k = 0; k < 4; ++k) v[k] = hp2[(size_t)u[k] * 32 + l];
#pragma unroll
    for (int k = 0; k < 4; ++k) {
      a0 += bflo(v[k].x); a1 += bfhi(v[k].x); a2 += bflo(v[k].y); a3 += bfhi(v[k].y);
    }
  }
  for (; i < cnt; ++i) {
    int u = ntl(csr_src + s + i);
    uint2 v = hp2[(size_t)u * 32 + l];
    a0 += bflo(v.x); a1 += bfhi(v.x); a2 += bflo(v.y); a3 += bfhi(v.y);
  }
  uint2 sv = hp2[(size_t)n * 32 + l];
  float4 bb = ((const float4*)bias)[l];
  float r0 = dn * (a0 + bflo(sv.x)) + bb.x;
  float r1 = dn * (a1 + bfhi(sv.x)) + bb.y;
  float r2 = dn * (a2 + bflo(sv.y)) + bb.z;
  float r3 = dn * (a3 + bfhi(sv.y)) + bb.w;
  ushort4 o; o.x = f2bf(r0); o.y = f2bf(r1); o.z = f2bf(r2); o.w = f2bf(r3);
  *(ushort4*)&outb[(size_t)n * DIM + l * 4] = o;
}

// ---------------- MFMA decode: 2 tiles/wave, upfront loads, XCD-swizzled, nt streams ----
__launch_bounds__(256)
__global__ void k_decode_mfma(const u16* __restrict__ z, const int* __restrict__ csr_src,
                              const int* __restrict__ csr_dst, const int* __restrict__ csr_eid,
                              float* __restrict__ out) {
  int l = threadIdx.x & 63;
  int r = l & 15, g = l >> 4;
  // bijective XCD swizzle over 12500 blocks: 12500 = 8*1562 + 4
  int bid = blockIdx.x;
  const int q = 1562, rm = 4;
  int xcd = bid & 7, idx = bid >> 3;
  int sw = (xcd < rm ? xcd * (q + 1) : rm * (q + 1) + (xcd - rm) * q) + idx;
  int tile0 = (sw * 4 + (threadIdx.x >> 6)) * 2;   // 2 tiles per wave; 100000 tiles total
  int p0 = tile0 * 16, p1 = p0 + 16;
  int s0 = ntl(csr_src + p0 + r), d0 = ntl(csr_dst + p0 + r), e0 = ntl(csr_eid + p0 + r);
  int s1 = ntl(csr_src + p1 + r), d1 = ntl(csr_dst + p1 + r), e1 = ntl(csr_eid + p1 + r);
  const bf16x8* za0 = (const bf16x8*)(z + (size_t)s0 * DIM + g * 8);
  const bf16x8* zb0 = (const bf16x8*)(z + (size_t)d0 * DIM + g * 8);
  const bf16x8* za1 = (const bf16x8*)(z + (size_t)s1 * DIM + g * 8);
  const bf16x8* zb1 = (const bf16x8*)(z + (size_t)d1 * DIM + g * 8);
  bf16x8 a0[4], b0[4], a1[4], b1[4];
#pragma unroll
  for (int ks = 0; ks < 4; ++ks) {
    a0[ks] = za0[ks * 4]; b0[ks] = zb0[ks * 4];
    a1[ks] = za1[ks * 4]; b1[ks] = zb1[ks * 4];
  }
  f32x4 acc0 = (f32x4){0.f, 0.f, 0.f, 0.f};
  f32x4 acc1 = (f32x4){0.f, 0.f, 0.f, 0.f};
#pragma unroll
  for (int ks = 0; ks < 4; ++ks) {
    acc0 = __builtin_amdgcn_mfma_f32_16x16x32_bf16(a0[ks], b0[ks], acc0, 0, 0, 0);
    acc1 = __builtin_amdgcn_mfma_f32_16x16x32_bf16(a1[ks], b1[ks], acc1, 0, 0, 0);
  }
  // diagonal D[r][r]: lane with (r>>2)==g holds rows g*4..g*4+3 of col r
  if ((r >> 2) == g) {
    __builtin_nontemporal_store(sigm(acc0[r & 3]), &out[e0]);
    __builtin_nontemporal_store(sigm(acc1[r & 3]), &out[e1]);
  }
}

extern "C" void kernel_launch(void* const* d_in, const int* in_sizes, int n_in,
                              void* d_out, int out_size, void* d_ws, size_t ws_size,
                              hipStream_t stream) {
  const float* x  = (const float*)d_in[0];
  const float* W1 = (const float*)d_in[1];
  const float* b1 = (const float*)d_in[2];
  const float* W2 = (const float*)d_in[3];
  const float* b2 = (const float*)d_in[4];
  const float* W3 = (const float*)d_in[5];
  const float* b3 = (const float*)d_in[6];
  const int*   ei = (const int*)d_in[7];
  const int* src = ei;
  const int* dst = ei + NE;
  float* out = (float*)d_out;

  char* w = (char*)d_ws;
  size_t p = 0;
  auto alloc = [&](size_t bytes) -> void* {
    void* r = w + p;
    p += (bytes + 255) & ~(size_t)255;
    return r;
  };
  int*   deg     = (int*)alloc((size_t)NN * 4);
  int*   offs    = (int*)alloc((size_t)NN * 4);
  float* dinv    = (float*)alloc((size_t)NN * 4);
  int*   bsum    = (int*)alloc(1024);
  int*   bcur    = (int*)alloc(512 * 4);
  uint2* bstage  = (uint2*)alloc((size_t)NE * 8);
  int*   csr_src = (int*)alloc((size_t)NE * 4);
  int*   csr_dst = (int*)alloc((size_t)NE * 4);
  int*   csr_eid = (int*)alloc((size_t)NE * 4);
  u16*   hp      = (u16*)alloc((size_t)NN * DIM * 2);
  u16*   hb      = (u16*)alloc((size_t)NN * DIM * 2);
  u16*   zb      = (u16*)alloc((size_t)NN * DIM * 2);
  u16*   Wp1     = (u16*)alloc(16384 * 2);
  u16*   Wp2     = (u16*)alloc(16384 * 2);
  u16*   Wp3     = (u16*)alloc(16384 * 2);
  (void)in_sizes; (void)n_in; (void)out_size; (void)ws_size;

  hipMemsetAsync(deg, 0, (size_t)NN * 4, stream);
  hipMemsetAsync(bcur, 0, 512 * 4, stream);

  k_deg<<<(NE + 255) / 256, 256, 0, stream>>>(dst, deg);
  int nb = (NN + SCHUNK - 1) / SCHUNK;  // 98
  k_scan1<<<nb, 256, 0, stream>>>(deg, bsum);
  k_scan2<<<1, 128, 0, stream>>>(bsum, nb);
  k_scan3<<<nb, 256, 0, stream>>>(deg, bsum, offs, dinv);

  int cb = (NE + ECH - 1) / ECH;  // 391
  k_bucket<<<cb, 256, 0, stream>>>(src, dst, offs, bcur, bstage);
  k_fillb<<<NBK, 256, 0, stream>>>(bstage, offs, csr_src, csr_dst, csr_eid);

  k_pack3<<<192, 256, 0, stream>>>(W1, W2, W3, Wp1, Wp2, Wp3);

  int gb = (NN + 63) / 64;  // 1563
  k_gemm1<<<gb, 256, 0, stream>>>(x, Wp1, dinv, hp);
  k_fused<<<NN / 32, 256, 0, stream>>>(hp, csr_src, offs, deg, dinv, b1, Wp2, hb);
  k_fused<<<NN / 32, 256, 0, stream>>>(hb, csr_src, offs, deg, dinv, b2, Wp3, hp);
  k_agg <<<NN / 8, 256, 0, stream>>>(hp, csr_src, offs, deg, dinv, b3, zb);
  // 100000 tiles / (4 waves * 2 tiles) = 12500 blocks
  k_decode_mfma<<<12500, 256, 0, stream>>>(zb, csr_src, csr_dst, csr_eid, out);
}

// Round 13
// 423.188 us; speedup vs baseline: 1.0868x; 1.0868x over previous
//
#include <hip/hip_runtime.h>
#include <math.h>

#define NN 100000
#define NE 1600000
#define DIM 128
#define SCHUNK 1024
#define NBK 391        // ceil(NN/256) buckets of 256 nodes
#define ECH 4096       // edges per k_bucket block

typedef unsigned short u16;
typedef unsigned int u32;
typedef unsigned long long u64;
typedef __attribute__((ext_vector_type(8))) short bf16x8;
typedef __attribute__((ext_vector_type(4))) float f32x4;

__device__ inline u16 f2bf(float f) {
  union { float f; u32 u; } v; v.f = f;
  u32 r = v.u + 0x7FFF + ((v.u >> 16) & 1);   // round-to-nearest-even
  return (u16)(r >> 16);
}
__device__ inline float bflo(u32 u) { union { u32 u; float f; } v; v.u = u << 16; return v.f; }
__device__ inline float bfhi(u32 u) { union { u32 u; float f; } v; v.u = u & 0xFFFF0000u; return v.f; }
__device__ inline float sigm(float x) { return 1.0f / (1.0f + expf(-x)); }

// ---------------- degree ----------------
__global__ void k_deg(const int* __restrict__ dst, int* __restrict__ deg) {
  int i = blockIdx.x * blockDim.x + threadIdx.x;
  if (i < NE) atomicAdd(&deg[dst[i]], 1);
}

// ---------------- exclusive prefix scan of deg -> offs (+ dinv fused) --------
__global__ void k_scan1(const int* __restrict__ deg, int* __restrict__ bsum) {
  __shared__ int sd[256];
  int t = threadIdx.x;
  int base = blockIdx.x * SCHUNK + t * 4;
  int s = 0;
#pragma unroll
  for (int j = 0; j < 4; ++j) { int idx = base + j; if (idx < NN) s += deg[idx]; }
  sd[t] = s; __syncthreads();
  for (int off = 128; off > 0; off >>= 1) {
    if (t < off) sd[t] += sd[t + off];
    __syncthreads();
  }
  if (t == 0) bsum[blockIdx.x] = sd[0];
}

__global__ void k_scan2(int* __restrict__ bsum, int nb) {   // nb <= 128
  __shared__ int sd[128];
  int t = threadIdx.x;
  int v = (t < nb) ? bsum[t] : 0;
  sd[t] = v; __syncthreads();
  for (int off = 1; off < 128; off <<= 1) {
    int x = (t >= off) ? sd[t - off] : 0;
    __syncthreads();
    sd[t] += x;
    __syncthreads();
  }
  if (t < nb) bsum[t] = sd[t] - v;
}

__global__ void k_scan3(const int* __restrict__ deg, const int* __restrict__ bsum,
                        int* __restrict__ offs, float* __restrict__ dinv) {
  __shared__ int ts[256];
  int t = threadIdx.x;
  int base = blockIdx.x * SCHUNK + t * 4;
  int v[4]; int loc = 0;
#pragma unroll
  for (int j = 0; j < 4; ++j) { int idx = base + j; v[j] = (idx < NN) ? deg[idx] : 0; loc += v[j]; }
  ts[t] = loc; __syncthreads();
  for (int off = 1; off < 256; off <<= 1) {
    int x = (t >= off) ? ts[t - off] : 0;
    __syncthreads();
    ts[t] += x;
    __syncthreads();
  }
  int run = bsum[blockIdx.x] + ts[t] - loc;
#pragma unroll
  for (int j = 0; j < 4; ++j) {
    int idx = base + j;
    if (idx < NN) {
      offs[idx] = run;
      dinv[idx] = rsqrtf((float)v[j] + 1.0f);
    }
    run += v[j];
  }
}

// ---------------- bucket pass: bin edges by dst>>8 into staging ----------------
__launch_bounds__(256)
__global__ void k_bucket(const int* __restrict__ src, const int* __restrict__ dst,
                         const int* __restrict__ offs, int* __restrict__ bcur,
                         uint2* __restrict__ bstage) {
  __shared__ int cnt[512];
  __shared__ int bl[512];
  __shared__ int gb[512];
  __shared__ int tmp[256];
  __shared__ uint2 st[ECH];
  int t = threadIdx.x;
  int e0 = blockIdx.x * ECH;
  cnt[t] = 0; cnt[t + 256] = 0;
  __syncthreads();
  int b_[16], r_[16]; u32 s_[16], y_[16];
#pragma unroll
  for (int k = 0; k < 16; ++k) {
    int i = e0 + k * 256 + t;
    b_[k] = -1;
    if (i < NE) {
      int d = dst[i];
      int bb = d >> 8;
      b_[k] = bb;
      s_[k] = (u32)src[i];
      y_[k] = ((u32)(d & 255) << 21) | (u32)i;
      r_[k] = atomicAdd(&cnt[bb], 1);
    }
  }
  __syncthreads();
  int c0 = cnt[2 * t], c1 = cnt[2 * t + 1];
  tmp[t] = c0 + c1;
  __syncthreads();
  for (int off = 1; off < 256; off <<= 1) {
    int v = (t >= off) ? tmp[t - off] : 0;
    __syncthreads();
    tmp[t] += v;
    __syncthreads();
  }
  int excl = tmp[t] - (c0 + c1);
  bl[2 * t] = excl; bl[2 * t + 1] = excl + c0;
  __syncthreads();
#pragma unroll
  for (int k = 0; k < 16; ++k)
    if (b_[k] >= 0) st[bl[b_[k]] + r_[k]] = make_uint2(s_[k], y_[k]);
  for (int b = t; b < 512; b += 256) {
    int n = cnt[b];
    gb[b] = (n > 0) ? atomicAdd(&bcur[b], n) : 0;
  }
  __syncthreads();
  for (int b = t; b < 512; b += 256) {
    int n = cnt[b];
    if (n > 0) {
      uint2* dp = bstage + offs[b << 8] + gb[b];
      const uint2* sp = st + bl[b];
      for (int j = 0; j < n; ++j) dp[j] = sp[j];
    }
  }
}

// ---------------- final fill: one block per bucket ----------------
// writes csr_src (for agg/fused) and csr_pack = src | dst<<17 | eid<<34 (for decode)
__launch_bounds__(256)
__global__ void k_fillb(const uint2* __restrict__ bstage, const int* __restrict__ offs,
                        int* __restrict__ csr_src, u64* __restrict__ csr_pack) {
  __shared__ int curl[256];
  int t = threadIdx.x;
  int b = blockIdx.x;
  int nb0 = b << 8;
  curl[t] = 0;
  __syncthreads();
  int sbase = offs[nb0];
  int send = (b == NBK - 1) ? NE : offs[nb0 + 256];
  for (int j = sbase + t; j < send; j += 256) {
    uint2 e = bstage[j];
    int dl = e.y >> 21;
    u64 eid = e.y & 0x1FFFFF;
    int pos = offs[nb0 + dl] + atomicAdd(&curl[dl], 1);
    csr_src[pos] = (int)e.x;
    csr_pack[pos] = (u64)e.x | ((u64)(nb0 + dl) << 17) | (eid << 34);
  }
}

// ---------------- pack all 3 W into MFMA B-frag order ----------------
__global__ void k_pack3(const float* __restrict__ W1, const float* __restrict__ W2,
                        const float* __restrict__ W3, u16* __restrict__ Wp1,
                        u16* __restrict__ Wp2, u16* __restrict__ Wp3) {
  int gid = blockIdx.x * blockDim.x + threadIdx.x;   // 3*16384
  int which = gid >> 14;
  int tid = gid & 16383;
  const float* W = which == 0 ? W1 : (which == 1 ? W2 : W3);
  u16* Wp = which == 0 ? Wp1 : (which == 1 ? Wp2 : Wp3);
  int b = tid & 7, j = (tid >> 3) & 15, kb = (tid >> 7) & 3, ks = (tid >> 9) & 3, ct = tid >> 11;
  int k = ks * 32 + kb * 8 + b, col = ct * 16 + j;
  Wp[tid] = f2bf(W[k * 128 + col]);
}

// ---------------- GEMM layer1: A = fp32 X (in-register cvt), W from global ----------------
__launch_bounds__(256)
__global__ void k_gemm1(const float* __restrict__ X, const u16* __restrict__ Wp,
                        const float* __restrict__ dinv, u16* __restrict__ hp) {
  __shared__ u16 ctile[4][2176];   // per-wave epilogue staging, 136-u16 row stride
  int t = threadIdx.x;
  int w = t >> 6, l = t & 63;
  int row0 = blockIdx.x * 64;
  int rbase = row0 + w * 16;

  int arow = rbase + (l & 15);
  arow = arow < NN ? arow : NN - 1;
  const float* ab = X + (size_t)arow * DIM + (l >> 4) * 8;
  bf16x8 a[4];
#pragma unroll
  for (int ks = 0; ks < 4; ++ks) {
    float4 f0 = *(const float4*)(ab + ks * 32);
    float4 f1 = *(const float4*)(ab + ks * 32 + 4);
    bf16x8 aa;
    aa[0] = (short)f2bf(f0.x); aa[1] = (short)f2bf(f0.y);
    aa[2] = (short)f2bf(f0.z); aa[3] = (short)f2bf(f0.w);
    aa[4] = (short)f2bf(f1.x); aa[5] = (short)f2bf(f1.y);
    aa[6] = (short)f2bf(f1.z); aa[7] = (short)f2bf(f1.w);
    a[ks] = aa;
  }

  f32x4 acc[8];
#pragma unroll
  for (int ct = 0; ct < 8; ++ct) {
    acc[ct] = (f32x4){0.f, 0.f, 0.f, 0.f};
#pragma unroll
    for (int ks = 0; ks < 4; ++ks) {
      bf16x8 bfr = *(const bf16x8*)&Wp[ct * 2048 + ks * 512 + (l >> 4) * 128 + (l & 15) * 8];
      acc[ct] = __builtin_amdgcn_mfma_f32_16x16x32_bf16(a[ks], bfr, acc[ct], 0, 0, 0);
    }
  }

  float dv[4];
#pragma unroll
  for (int v = 0; v < 4; ++v) {
    int rr = rbase + (l >> 4) * 4 + v;
    dv[v] = dinv[rr < NN ? rr : NN - 1];
  }
  u16* ct_lds = ctile[w];
#pragma unroll
  for (int ct = 0; ct < 8; ++ct) {
#pragma unroll
    for (int v = 0; v < 4; ++v) {
      int row = (l >> 4) * 4 + v;
      ct_lds[row * 136 + ct * 16 + (l & 15)] = f2bf(dv[v] * acc[ct][v]);
    }
  }
  __syncthreads();
#pragma unroll
  for (int rr = 0; rr < 4; ++rr) {
    int row = rr * 4 + (l >> 4);
    int grow = rbase + row;
    if (grow < NN)
      *(uint4*)&hp[(size_t)grow * DIM + (l & 15) * 8] =
          *(const uint4*)&ct_lds[row * 136 + (l & 15) * 8];
  }
}

// ---------------- FUSED: agg(layer l) + GEMM(layer l+1), 32 rows/block ----------------
__launch_bounds__(256)
__global__ void k_fused(const u16* __restrict__ hp, const int* __restrict__ csr_src,
                        const int* __restrict__ offs, const int* __restrict__ deg,
                        const float* __restrict__ dinv, const float* __restrict__ bias,
                        const u16* __restrict__ Wp, u16* __restrict__ hpo) {
  __shared__ u16 atile[4352];      // gather: 32 rows x 256 B swizzled (4096 u16);
                                   // reused as ctile: 4 waves x 16 x 68 (4352 u16)
  int t = threadIdx.x;
  int row0 = blockIdx.x * 32;      // NN = 3125 * 32 exact

  // ---- gather (agg) phase: 8 groups x 32 lanes, 4 passes ----
  {
    int g = t >> 5, l = t & 31;
    const uint2* hp2 = (const uint2*)hp;
    float4 bb = ((const float4*)bias)[l];
    for (int pass = 0; pass < 4; ++pass) {
      int row = pass * 8 + g;
      int n = row0 + row;
      float dn = dinv[n];
      int s = offs[n], cnt = deg[n];
      float a0 = 0.f, a1 = 0.f, a2 = 0.f, a3 = 0.f;
      int i = 0;
      for (; i + 8 <= cnt; i += 8) {
        int u[8];
#pragma unroll
        for (int k = 0; k < 8; ++k) u[k] = csr_src[s + i + k];
        uint2 v[8];
#pragma unroll
        for (int k = 0; k < 8; ++k) v[k] = hp2[(size_t)u[k] * 32 + l];
#pragma unroll
        for (int k = 0; k < 8; ++k) {
          a0 += bflo(v[k].x); a1 += bfhi(v[k].x); a2 += bflo(v[k].y); a3 += bfhi(v[k].y);
        }
      }
      for (; i + 4 <= cnt; i += 4) {
        int u[4];
#pragma unroll
        for (int k = 0; k < 4; ++k) u[k] = csr_src[s + i + k];
        uint2 v[4];
#pragma unroll
        for (int k = 0; k < 4; ++k) v[k] = hp2[(size_t)u[k] * 32 + l];
#pragma unroll
        for (int k = 0; k < 4; ++k) {
          a0 += bflo(v[k].x); a1 += bfhi(v[k].x); a2 += bflo(v[k].y); a3 += bfhi(v[k].y);
        }
      }
      for (; i < cnt; ++i) {
        int u = csr_src[s + i];
        uint2 v = hp2[(size_t)u * 32 + l];
        a0 += bflo(v.x); a1 += bfhi(v.x); a2 += bflo(v.y); a3 += bfhi(v.y);
      }
      uint2 sv = hp2[(size_t)n * 32 + l];
      float r0 = fmaxf(dn * (a0 + bflo(sv.x)) + bb.x, 0.f);
      float r1 = fmaxf(dn * (a1 + bfhi(sv.x)) + bb.y, 0.f);
      float r2 = fmaxf(dn * (a2 + bflo(sv.y)) + bb.z, 0.f);
      float r3 = fmaxf(dn * (a3 + bfhi(sv.y)) + bb.w, 0.f);
      ushort4 o; o.x = f2bf(r0); o.y = f2bf(r1); o.z = f2bf(r2); o.w = f2bf(r3);
      int byte = row * 256 + ((l * 8) ^ ((row & 7) << 4));
      *(ushort4*)((char*)atile + byte) = o;
    }
  }
  __syncthreads();

  // ---- GEMM phase: 4 waves = (row half) x (col half); 16 rows x 64 cols each ----
  int w = t >> 6, l = t & 63;
  int rbase = row0 + (w & 1) * 16;
  int arow = (w & 1) * 16 + (l & 15);
  int chalf = w >> 1;
  bf16x8 a[4];
#pragma unroll
  for (int ks = 0; ks < 4; ++ks) {
    int cb = ((l >> 4) * 16 + ks * 64) ^ ((arow & 7) << 4);
    a[ks] = *(const bf16x8*)((const char*)atile + arow * 256 + cb);
  }
  f32x4 acc[4];
#pragma unroll
  for (int ct = 0; ct < 4; ++ct) {
    int ctg = chalf * 4 + ct;
    acc[ct] = (f32x4){0.f, 0.f, 0.f, 0.f};
#pragma unroll
    for (int ks = 0; ks < 4; ++ks) {
      bf16x8 bfr = *(const bf16x8*)&Wp[ctg * 2048 + ks * 512 + (l >> 4) * 128 + (l & 15) * 8];
      acc[ct] = __builtin_amdgcn_mfma_f32_16x16x32_bf16(a[ks], bfr, acc[ct], 0, 0, 0);
    }
  }
  __syncthreads();   // all atile reads done before ctile reuse

  float dv[4];
#pragma unroll
  for (int v = 0; v < 4; ++v) dv[v] = dinv[rbase + (l >> 4) * 4 + v];
  u16* ct_lds = atile + w * 1088;    // 16 rows x 68 u16 per wave
#pragma unroll
  for (int ct = 0; ct < 4; ++ct) {
#pragma unroll
    for (int v = 0; v < 4; ++v) {
      int row = (l >> 4) * 4 + v;
      ct_lds[row * 68 + ct * 16 + (l & 15)] = f2bf(dv[v] * acc[ct][v]);
    }
  }
  __syncthreads();
#pragma unroll
  for (int rr = 0; rr < 2; ++rr) {
    int row = rr * 8 + (l >> 3);
    int grow = rbase + row;
    *(uint4*)&hpo[(size_t)grow * DIM + chalf * 64 + (l & 7) * 8] =
        *(const uint4*)&ct_lds[row * 68 + (l & 7) * 8];
  }
}

// ---------------- layer-3 aggregation: z = bf16( dn*(sum hp[u] + hp[n]) + b ) ----
__launch_bounds__(256)
__global__ void k_agg(const u16* __restrict__ hp, const int* __restrict__ csr_src,
                      const int* __restrict__ offs, const int* __restrict__ deg,
                      const float* __restrict__ dinv, const float* __restrict__ bias,
                      u16* __restrict__ outb) {
  int t = threadIdx.x;
  int g = t >> 5, l = t & 31;
  int n = blockIdx.x * 8 + g;          // NN/8 exact
  float dn = dinv[n];
  int s = offs[n], cnt = deg[n];
  const uint2* hp2 = (const uint2*)hp;
  float a0 = 0.f, a1 = 0.f, a2 = 0.f, a3 = 0.f;
  int i = 0;
  for (; i + 8 <= cnt; i += 8) {
    int u[8];
#pragma unroll
    for (int k = 0; k < 8; ++k) u[k] = csr_src[s + i + k];
    uint2 v[8];
#pragma unroll
    for (int k = 0; k < 8; ++k) v[k] = hp2[(size_t)u[k] * 32 + l];
#pragma unroll
    for (int k = 0; k < 8; ++k) {
      a0 += bflo(v[k].x); a1 += bfhi(v[k].x); a2 += bflo(v[k].y); a3 += bfhi(v[k].y);
    }
  }
  for (; i + 4 <= cnt; i += 4) {
    int u[4];
#pragma unroll
    for (int k = 0; k < 4; ++k) u[k] = csr_src[s + i + k];
    uint2 v[4];
#pragma unroll
    for (int k = 0; k < 4; ++k) v[k] = hp2[(size_t)u[k] * 32 + l];
#pragma unroll
    for (int k = 0; k < 4; ++k) {
      a0 += bflo(v[k].x); a1 += bfhi(v[k].x); a2 += bflo(v[k].y); a3 += bfhi(v[k].y);
    }
  }
  for (; i < cnt; ++i) {
    int u = csr_src[s + i];
    uint2 v = hp2[(size_t)u * 32 + l];
    a0 += bflo(v.x); a1 += bfhi(v.x); a2 += bflo(v.y); a3 += bfhi(v.y);
  }
  uint2 sv = hp2[(size_t)n * 32 + l];
  float4 bb = ((const float4*)bias)[l];
  float r0 = dn * (a0 + bflo(sv.x)) + bb.x;
  float r1 = dn * (a1 + bfhi(sv.x)) + bb.y;
  float r2 = dn * (a2 + bflo(sv.y)) + bb.z;
  float r3 = dn * (a3 + bfhi(sv.y)) + bb.w;
  ushort4 o; o.x = f2bf(r0); o.y = f2bf(r1); o.z = f2bf(r2); o.w = f2bf(r3);
  *(ushort4*)&outb[(size_t)n * DIM + l * 4] = o;
}

// ---------------- MFMA decode: 2 tiles/wave, packed-u64 CSR, XCD-swizzled ----------------
__launch_bounds__(256)
__global__ void k_decode_mfma(const u16* __restrict__ z, const u64* __restrict__ csr_pack,
                              float* __restrict__ out) {
  int l = threadIdx.x & 63;
  int r = l & 15, g = l >> 4;
  // bijective XCD swizzle over 12500 blocks: 12500 = 8*1562 + 4
  int bid = blockIdx.x;
  const int q = 1562, rm = 4;
  int xcd = bid & 7, idx = bid >> 3;
  int sw = (xcd < rm ? xcd * (q + 1) : rm * (q + 1) + (xcd - rm) * q) + idx;
  int tile0 = (sw * 4 + (threadIdx.x >> 6)) * 2;   // 2 tiles per wave; 100000 tiles total
  int p0 = tile0 * 16, p1 = p0 + 16;
  u64 ev0 = csr_pack[p0 + r];
  u64 ev1 = csr_pack[p1 + r];
  int s0 = (int)(ev0 & 0x1FFFF), d0 = (int)((ev0 >> 17) & 0x1FFFF), e0 = (int)(ev0 >> 34);
  int s1 = (int)(ev1 & 0x1FFFF), d1 = (int)((ev1 >> 17) & 0x1FFFF), e1 = (int)(ev1 >> 34);
  const bf16x8* za0 = (const bf16x8*)(z + (size_t)s0 * DIM + g * 8);
  const bf16x8* zb0 = (const bf16x8*)(z + (size_t)d0 * DIM + g * 8);
  const bf16x8* za1 = (const bf16x8*)(z + (size_t)s1 * DIM + g * 8);
  const bf16x8* zb1 = (const bf16x8*)(z + (size_t)d1 * DIM + g * 8);
  bf16x8 a0[4], b0[4], a1[4], b1[4];
#pragma unroll
  for (int ks = 0; ks < 4; ++ks) {
    a0[ks] = za0[ks * 4]; b0[ks] = zb0[ks * 4];
    a1[ks] = za1[ks * 4]; b1[ks] = zb1[ks * 4];
  }
  f32x4 acc0 = (f32x4){0.f, 0.f, 0.f, 0.f};
  f32x4 acc1 = (f32x4){0.f, 0.f, 0.f, 0.f};
#pragma unroll
  for (int ks = 0; ks < 4; ++ks) {
    acc0 = __builtin_amdgcn_mfma_f32_16x16x32_bf16(a0[ks], b0[ks], acc0, 0, 0, 0);
    acc1 = __builtin_amdgcn_mfma_f32_16x16x32_bf16(a1[ks], b1[ks], acc1, 0, 0, 0);
  }
  // diagonal D[r][r]: lane with (r>>2)==g holds rows g*4..g*4+3 of col r
  if ((r >> 2) == g) {
    out[e0] = sigm(acc0[r & 3]);
    out[e1] = sigm(acc1[r & 3]);
  }
}

extern "C" void kernel_launch(void* const* d_in, const int* in_sizes, int n_in,
                              void* d_out, int out_size, void* d_ws, size_t ws_size,
                              hipStream_t stream) {
  const float* x  = (const float*)d_in[0];
  const float* W1 = (const float*)d_in[1];
  const float* b1 = (const float*)d_in[2];
  const float* W2 = (const float*)d_in[3];
  const float* b2 = (const float*)d_in[4];
  const float* W3 = (const float*)d_in[5];
  const float* b3 = (const float*)d_in[6];
  const int*   ei = (const int*)d_in[7];
  const int* src = ei;
  const int* dst = ei + NE;
  float* out = (float*)d_out;

  char* w = (char*)d_ws;
  size_t p = 0;
  auto alloc = [&](size_t bytes) -> void* {
    void* r = w + p;
    p += (bytes + 255) & ~(size_t)255;
    return r;
  };
  int*   deg      = (int*)alloc((size_t)NN * 4);
  int*   offs     = (int*)alloc((size_t)NN * 4);
  float* dinv     = (float*)alloc((size_t)NN * 4);
  int*   bsum     = (int*)alloc(1024);
  int*   bcur     = (int*)alloc(512 * 4);
  uint2* bstage   = (uint2*)alloc((size_t)NE * 8);
  int*   csr_src  = (int*)alloc((size_t)NE * 4);
  u64*   csr_pack = (u64*)alloc((size_t)NE * 8);
  u16*   hp       = (u16*)alloc((size_t)NN * DIM * 2);
  u16*   hb       = (u16*)alloc((size_t)NN * DIM * 2);
  u16*   zb       = (u16*)alloc((size_t)NN * DIM * 2);
  u16*   Wp1      = (u16*)alloc(16384 * 2);
  u16*   Wp2      = (u16*)alloc(16384 * 2);
  u16*   Wp3      = (u16*)alloc(16384 * 2);
  (void)in_sizes; (void)n_in; (void)out_size; (void)ws_size;

  hipMemsetAsync(deg, 0, (size_t)NN * 4, stream);
  hipMemsetAsync(bcur, 0, 512 * 4, stream);

  k_deg<<<(NE + 255) / 256, 256, 0, stream>>>(dst, deg);
  int nb = (NN + SCHUNK - 1) / SCHUNK;  // 98
  k_scan1<<<nb, 256, 0, stream>>>(deg, bsum);
  k_scan2<<<1, 128, 0, stream>>>(bsum, nb);
  k_scan3<<<nb, 256, 0, stream>>>(deg, bsum, offs, dinv);

  int cb = (NE + ECH - 1) / ECH;  // 391
  k_bucket<<<cb, 256, 0, stream>>>(src, dst, offs, bcur, bstage);
  k_fillb<<<NBK, 256, 0, stream>>>(bstage, offs, csr_src, csr_pack);

  k_pack3<<<192, 256, 0, stream>>>(W1, W2, W3, Wp1, Wp2, Wp3);

  int gb = (NN + 63) / 64;  // 1563
  k_gemm1<<<gb, 256, 0, stream>>>(x, Wp1, dinv, hp);
  k_fused<<<NN / 32, 256, 0, stream>>>(hp, csr_src, offs, deg, dinv, b1, Wp2, hb);
  k_fused<<<NN / 32, 256, 0, stream>>>(hb, csr_src, offs, deg, dinv, b2, Wp3, hp);
  k_agg <<<NN / 8, 256, 0, stream>>>(hp, csr_src, offs, deg, dinv, b3, zb);
  // 100000 tiles / (4 waves * 2 tiles) = 12500 blocks
  k_decode_mfma<<<12500, 256, 0, stream>>>(zb, csr_pack, out);
}